// Round 11
// baseline (307.665 us; speedup 1.0000x reference)
//
#include <hip/hip_runtime.h>
#include <stdint.h>

#define B_  16
#define V_  512
#define S_  1024
#define E_  8
#define FF_ 2048
#define NT_ (B_*V_)    // 8192 tokens (b,v)
#define NR_ (B_*S_)    // 16384 rows (b,s)

typedef __attribute__((ext_vector_type(8))) short bf16x8;   // 8 bf16 = 4 VGPRs
typedef __attribute__((ext_vector_type(4))) float f32x4;

__device__ __forceinline__ unsigned short f2bf(float f) {
    unsigned int u = __float_as_uint(f);
    u += 0x7FFFu + ((u >> 16) & 1u);          // round-to-nearest-even
    return (unsigned short)(u >> 16);
}
__device__ __forceinline__ float bf2f(unsigned short u) {
    return __uint_as_float(((unsigned int)u) << 16);
}

__device__ __forceinline__ void gl_lds16(const void* g, void* l) {
    // async global->LDS, 16B per lane; LDS dest = wave-uniform base + lane*16
    __builtin_amdgcn_global_load_lds((const __attribute__((address_space(1))) void*)g,
                                     (__attribute__((address_space(3))) void*)l,
                                     16, 0, 0);
}

// ---------------- fused prep: weight fp32->bf16 convert  +  xt transpose  +  gate partials ----------------
__device__ __forceinline__ void cvt4(const float* s, unsigned short* d, int i) {
    float4 v = *(const float4*)(s + i);
    ushort4 o; o.x = f2bf(v.x); o.y = f2bf(v.y); o.z = f2bf(v.z); o.w = f2bf(v.w);
    *(ushort4*)(d + i) = o;
}
// grid (16, 8, 56): z<16 -> xt_gate path (b=z, sc=y, vt=x);
// z>=16 -> convert path, linear id = (z-16)*128 + y*16 + x in [0,5120), 2 float4-groups each.
__global__ __launch_bounds__(256) void k_prep(const float* __restrict__ x,
                                              const float* __restrict__ gate_W,
                                              unsigned short* __restrict__ xt,
                                              double* __restrict__ part,
                                              int* __restrict__ cnt,
                                              const float* __restrict__ expW, unsigned short* __restrict__ expWb,
                                              const float* __restrict__ fc1W, unsigned short* __restrict__ fc1Wb,
                                              const float* __restrict__ fc2W, unsigned short* __restrict__ fc2Wb) {
    int tid = threadIdx.x;
    if (blockIdx.z >= 16) {
        int cid = ((int)blockIdx.z - 16) * 128 + (int)blockIdx.y * 16 + (int)blockIdx.x;
        #pragma unroll
        for (int rep = 0; rep < 2; ++rep) {
            int g = (cid + rep * 5120) * 256 + tid;          // [0, 2621440)
            if (g < 2097152)              cvt4(expW, expWb, g * 4);
            else if (g < 2097152 + 262144) cvt4(fc1W, fc1Wb, (g - 2097152) * 4);
            else                           cvt4(fc2W, fc2Wb, (g - 2097152 - 262144) * 4);
        }
        return;
    }
    __shared__ float t[32][33];
    __shared__ float gw[E_][128];
    int b = blockIdx.z, sc = blockIdx.y, vt = blockIdx.x;   // sc: 128-s chunk
    if (vt == 0 && sc == 0 && b == 0 && tid < E_) cnt[tid] = 0;
    int col = tid & 31, row8 = tid >> 5;
    for (int i = tid; i < E_ * 128; i += 256) {
        int e = i >> 7, j = i & 127;
        gw[e][j] = gate_W[e * S_ + sc * 128 + j];
    }
    double acc = 0.0;
    for (int sub = 0; sub < 4; ++sub) {
        int s0 = sc * 128 + sub * 32;
        __syncthreads();                       // gw ready (sub=0) / t readers done (sub>0)
        for (int r = 0; r < 4; ++r) {
            int sl = row8 + r * 8;
            t[sl][col] = x[(b * S_ + s0 + sl) * V_ + vt * 32 + col];   // t[s][v]
        }
        __syncthreads();
        for (int r = 0; r < 4; ++r) {
            int vl = row8 + r * 8;
            xt[(size_t)(b * V_ + vt * 32 + vl) * S_ + s0 + col] = f2bf(t[col][vl]);
        }
        #pragma unroll
        for (int s = 0; s < 32; ++s)
            acc += (double)t[s][col] * (double)gw[row8][sub * 32 + s];
    }
    int tok = b * V_ + vt * 32 + col;
    part[((size_t)sc * NT_ + tok) * E_ + row8] = acc;
}

// ---------------- gating stage B: reduce 8 chunks, softmax, top-2, routing ----------------
__global__ __launch_bounds__(256) void k_gate_fin(const double* __restrict__ part,
                                                  float* __restrict__ probs_out,
                                                  int* __restrict__ cnt, int* __restrict__ tok_of,
                                                  int* __restrict__ tk_slot, float* __restrict__ tk_w) {
    int t = blockIdx.x * 256 + threadIdx.x;
    int lane = threadIdx.x & 63;
    double l[E_];
    #pragma unroll
    for (int e = 0; e < E_; ++e) l[e] = 0.0;
    for (int c = 0; c < S_ / 128; ++c) {
        const double* p = part + ((size_t)c * NT_ + t) * E_;
        #pragma unroll
        for (int e = 0; e < E_; ++e) l[e] += p[e];
    }
    double m = l[0];
    #pragma unroll
    for (int e = 1; e < E_; ++e) m = l[e] > m ? l[e] : m;
    double p[E_], sum = 0.0;
    #pragma unroll
    for (int e = 0; e < E_; ++e) { p[e] = exp(l[e] - m); sum += p[e]; }
    float pf[E_];
    #pragma unroll
    for (int e = 0; e < E_; ++e) pf[e] = (float)(p[e] / sum);
    float4 pa = {pf[0], pf[1], pf[2], pf[3]}, pb = {pf[4], pf[5], pf[6], pf[7]};
    *(float4*)(probs_out + (size_t)t * E_) = pa;
    *(float4*)(probs_out + (size_t)t * E_ + 4) = pb;
    int i0 = 0;
    #pragma unroll
    for (int e = 1; e < E_; ++e) if (pf[e] > pf[i0]) i0 = e;
    int i1 = -1;
    #pragma unroll
    for (int e = 0; e < E_; ++e) if (e != i0 && (i1 < 0 || pf[e] > pf[i1])) i1 = e;
    int sel[2] = {i0, i1};
    float wsel[2] = {pf[i0], pf[i1]};
    #pragma unroll
    for (int k = 0; k < 2; ++k) {
        int ie = sel[k];
        int pos = 0;
        for (int e = 0; e < E_; ++e) {                       // uniform loop, ballot legal
            unsigned long long msk = __ballot(ie == e);
            if (ie == e) {
                int rank = __popcll(msk & ((1ull << lane) - 1ull));
                int leader = __ffsll((long long)msk) - 1;
                int base = 0;
                if (lane == leader) base = atomicAdd(&cnt[e], __popcll(msk));
                base = __shfl(base, leader);
                pos = base + rank;
            }
        }
        tok_of[ie * NT_ + pos] = t;
        tk_slot[t * 2 + k] = (ie << 16) | pos;
        tk_w[t * 2 + k] = wsel[k];
    }
}

// ---------------- 128^2 K-loop (known-good): BK=64, 16x16x32 MFMA, XOR-swizzled LDS ----------------
__device__ __forceinline__ void gemm_k_loop64(const unsigned short* (&ap)[4],
                                              const unsigned short* (&bp)[4],
                                              short* As, short* Bs, int kIters, int wave, int lane,
                                              f32x4 (&acc)[4][4]) {
    char* ldsA = (char*)As + wave * 4096;
    char* ldsB = (char*)Bs + wave * 4096;
    int wm = (wave & 1) << 6, wn = (wave >> 1) << 6;
    int lr = lane & 15, quad = lane >> 4;
    int pb = (quad ^ (lr & 7)) * 8;
    const unsigned short* a0 = ap[0]; const unsigned short* a1 = ap[1];
    const unsigned short* a2 = ap[2]; const unsigned short* a3 = ap[3];
    const unsigned short* b0 = bp[0]; const unsigned short* b1 = bp[1];
    const unsigned short* b2 = bp[2]; const unsigned short* b3 = bp[3];
    for (int kk = 0; kk < kIters; ++kk) {
        gl_lds16(a0, ldsA);        gl_lds16(a1, ldsA + 1024);
        gl_lds16(a2, ldsA + 2048); gl_lds16(a3, ldsA + 3072);
        gl_lds16(b0, ldsB);        gl_lds16(b1, ldsB + 1024);
        gl_lds16(b2, ldsB + 2048); gl_lds16(b3, ldsB + 3072);
        a0 += 64; a1 += 64; a2 += 64; a3 += 64;
        b0 += 64; b1 += 64; b2 += 64; b3 += 64;
        __syncthreads();
        #pragma unroll
        for (int ks = 0; ks < 2; ++ks) {
            int po = pb ^ (ks << 5);
            bf16x8 af[4], bfv[4];
            #pragma unroll
            for (int i = 0; i < 4; ++i)
                af[i] = *(const bf16x8*)(As + (wm + i * 16 + lr) * 64 + po);
            #pragma unroll
            for (int j = 0; j < 4; ++j)
                bfv[j] = *(const bf16x8*)(Bs + (wn + j * 16 + lr) * 64 + po);
            #pragma unroll
            for (int i = 0; i < 4; ++i)
                #pragma unroll
                for (int j = 0; j < 4; ++j)
                    acc[i][j] = __builtin_amdgcn_mfma_f32_16x16x32_bf16(af[i], bfv[j], acc[i][j], 0, 0, 0);
        }
        __syncthreads();
    }
}

// ---------------- MoE gather-GEMM: Yb = bf16(xt[tok] @ expW[e]^T + exp_b) ----------------
// launch_bounds(256,3): reg footprint ~72 arch VGPR + 64 acc AGPR = 136/wave -> 3 waves/SIMD
// ceiling. (256,5) spills acc (R4: WRITE_SIZE 33->591 MB). Do not raise.
__global__ __launch_bounds__(256, 3) void k_moe_gemm(const unsigned short* __restrict__ xt,
                                                     const unsigned short* __restrict__ expWb,
                                                     const float* __restrict__ exp_b,
                                                     const int* __restrict__ cnt,
                                                     const int* __restrict__ tok_of,
                                                     unsigned short* __restrict__ Yb) {
    int bx = ((int)(blockIdx.x & 7)) * 17 + (int)(blockIdx.x >> 3);   // 136 = 8*17 bijective XCD swizzle
    int e = -1, pos0 = 0, yrow0 = 0, ne = 0;
    {
        int tb = 0, o = 0;
        #pragma unroll
        for (int i = 0; i < E_; ++i) {
            int ci = cnt[i];
            int nti = (ci + 127) >> 7;
            if (e < 0 && bx < tb + nti) { e = i; pos0 = (bx - tb) * 128; yrow0 = o; ne = ci; }
            tb += nti; o += ci;
        }
    }
    if (e < 0) return;
    int nt = blockIdx.y;
    __shared__ __align__(16) short As[128 * 64];   // 16 KB
    __shared__ __align__(16) short Bs[128 * 64];   // 16 KB
    int tid = threadIdx.x, wave = tid >> 6, lane = tid & 63;
    int rowLoc = wave * 32 + (lane >> 3);
    int cg = ((lane & 7) ^ ((lane >> 3) & 7)) * 8;
    const unsigned short* Wb = expWb + (size_t)e * S_ * S_;
    const unsigned short* ap[4];
    const unsigned short* bp[4];
    #pragma unroll
    for (int c = 0; c < 4; ++c) {
        int rr = rowLoc + c * 8;
        int tok = tok_of[e * NT_ + min(pos0 + rr, ne - 1)];
        ap[c] = xt + (size_t)tok * S_ + cg;
        bp[c] = Wb + (size_t)(nt * 128 + rr) * S_ + cg;
    }
    f32x4 acc[4][4] = {};
    gemm_k_loop64(ap, bp, As, Bs, S_ / 64, wave, lane, acc);
    int wm = (wave & 1) << 6, wn = (wave >> 1) << 6;
    int lr = lane & 15, quad = lane >> 4;
    #pragma unroll
    for (int i = 0; i < 4; ++i)
        #pragma unroll
        for (int r = 0; r < 4; ++r) {
            int pos = pos0 + wm + i * 16 + quad * 4 + r;
            if (pos < ne) {
                size_t row = (size_t)(yrow0 + pos);
                #pragma unroll
                for (int j = 0; j < 4; ++j) {
                    int col = nt * 128 + wn + j * 16 + lr;
                    Yb[row * S_ + col] = f2bf(acc[i][j][r] + exp_b[e * S_ + col]);
                }
            }
        }
}

// ---------------- combine: x2b[b,s,v] = bf16(x + relu(w0*Y0 + w1*Y1)) ----------------
__global__ void k_combine(const float* __restrict__ x, const unsigned short* __restrict__ Yb,
                          const int* __restrict__ cnt, const int* __restrict__ tk_slot,
                          const float* __restrict__ tk_w,
                          unsigned short* __restrict__ x2b) {
    __shared__ float t[32][33];
    int b = blockIdx.z, st = blockIdx.y, vt = blockIdx.x;
    int tid = threadIdx.x;
    int vl = tid >> 3, sq = (tid & 7) * 4;
    int tok = b * V_ + vt * 32 + vl;
    int s0 = tk_slot[tok * 2 + 0], s1 = tk_slot[tok * 2 + 1];
    float w0 = tk_w[tok * 2 + 0], w1 = tk_w[tok * 2 + 1];
    int e0 = s0 >> 16, e1 = s1 >> 16;
    int r0b = 0, r1b = 0, o = 0;
    #pragma unroll
    for (int i = 0; i < E_; ++i) {
        if (i == e0) r0b = o;
        if (i == e1) r1b = o;
        o += cnt[i];
    }
    size_t r0 = (size_t)(r0b + (s0 & 0xFFFF));
    size_t r1 = (size_t)(r1b + (s1 & 0xFFFF));
    int sg = st * 32 + sq;
    ushort4 y0 = *(const ushort4*)(Yb + r0 * S_ + sg);
    ushort4 y1 = *(const ushort4*)(Yb + r1 * S_ + sg);
    t[vl][sq + 0] = fmaxf(w0 * bf2f(y0.x) + w1 * bf2f(y1.x), 0.f);
    t[vl][sq + 1] = fmaxf(w0 * bf2f(y0.y) + w1 * bf2f(y1.y), 0.f);
    t[vl][sq + 2] = fmaxf(w0 * bf2f(y0.z) + w1 * bf2f(y1.z), 0.f);
    t[vl][sq + 3] = fmaxf(w0 * bf2f(y0.w) + w1 * bf2f(y1.w), 0.f);
    __syncthreads();
    int vcol = tid & 31, srow8 = tid >> 5;
    for (int r = 0; r < 4; ++r) {
        int sl = srow8 + r * 8;
        size_t gi = (size_t)(b * S_ + st * 32 + sl) * V_ + vt * 32 + vcol;
        x2b[gi] = f2bf(x[gi] + t[vcol][sl]);
    }
}

// ================= 256x256 8-wave deep-pipelined GEMM (fc1) =================
__device__ __forceinline__ void stage8(const unsigned short* (&ap)[4],
                                       const unsigned short* (&bp)[4],
                                       char* ldsA, char* ldsB, int kt, int wave) {
    const int off = kt * 64;                  // shorts
    char* la = ldsA + wave * 4096;            // wave stages rows [wave*32, +32): 4 x 1KB
    char* lb = ldsB + wave * 4096;
    gl_lds16(ap[0] + off, la);
    gl_lds16(ap[1] + off, la + 1024);
    gl_lds16(ap[2] + off, la + 2048);
    gl_lds16(ap[3] + off, la + 3072);
    gl_lds16(bp[0] + off, lb);
    gl_lds16(bp[1] + off, lb + 1024);
    gl_lds16(bp[2] + off, lb + 2048);
    gl_lds16(bp[3] + off, lb + 3072);
}

template<bool LAST>
__device__ __forceinline__ void body64(const short* As, const short* Bs,
                                       int wmBase, int wnBase, int lr, int pb,
                                       f32x4 (&acc)[8][4]) {
    if (LAST) asm volatile("s_waitcnt vmcnt(0)" ::: "memory");
    else      asm volatile("s_waitcnt vmcnt(8)" ::: "memory");
    __builtin_amdgcn_s_barrier();
    __builtin_amdgcn_sched_barrier(0);
    bf16x8 bfv[4][2];
    #pragma unroll
    for (int j = 0; j < 4; ++j)
        #pragma unroll
        for (int ks = 0; ks < 2; ++ks)
            bfv[j][ks] = *(const bf16x8*)(Bs + (wnBase + j * 16 + lr) * 64 + (pb ^ (ks << 5)));
    #pragma unroll
    for (int q = 0; q < 4; ++q) {
        bf16x8 af[2][2];
        #pragma unroll
        for (int f = 0; f < 2; ++f)
            #pragma unroll
            for (int ks = 0; ks < 2; ++ks)
                af[f][ks] = *(const bf16x8*)(As + (wmBase + q * 32 + f * 16 + lr) * 64 + (pb ^ (ks << 5)));
        __builtin_amdgcn_s_barrier();
        __builtin_amdgcn_s_setprio(1);
        #pragma unroll
        for (int f = 0; f < 2; ++f)
            #pragma unroll
            for (int j = 0; j < 4; ++j)
                #pragma unroll
                for (int ks = 0; ks < 2; ++ks)
                    acc[q * 2 + f][j] = __builtin_amdgcn_mfma_f32_16x16x32_bf16(
                        af[f][ks], bfv[j][ks], acc[q * 2 + f][j], 0, 0, 0);
        __builtin_amdgcn_s_setprio(0);
        __builtin_amdgcn_s_barrier();
    }
}

template<int KT>
__device__ __forceinline__ void gemm8(const unsigned short* (&ap)[4],
                                      const unsigned short* (&bp)[4],
                                      char* smem, int wave, int lane,
                                      f32x4 (&acc)[8][4]) {
    char* A0 = smem;           char* B0 = smem + 32768;
    char* A1 = smem + 65536;   char* B1 = smem + 98304;
    const int wmBase = (wave >> 2) * 128;     // 2 M-waves x 4 N-waves
    const int wnBase = (wave & 3) * 64;
    const int lr = lane & 15;
    const int pb = ((lane >> 4) ^ (lr & 7)) * 8;
    stage8(ap, bp, A0, B0, 0, wave);
    stage8(ap, bp, A1, B1, 1, wave);
    for (int kt = 0; kt + 2 < KT; kt += 2) {
        body64<false>((const short*)A0, (const short*)B0, wmBase, wnBase, lr, pb, acc);
        stage8(ap, bp, A0, B0, kt + 2, wave);
        body64<false>((const short*)A1, (const short*)B1, wmBase, wnBase, lr, pb, acc);
        stage8(ap, bp, A1, B1, kt + 3, wave);
    }
    body64<false>((const short*)A0, (const short*)B0, wmBase, wnBase, lr, pb, acc);
    body64<true >((const short*)A1, (const short*)B1, wmBase, wnBase, lr, pb, acc);
}

// ---------------- fc1 (8-phase 256^2): h = relu(x2b @ fc1W^T + b) -> bf16 ----------------
// R9 LESSON: keep the 2D grid (x=m fast, y=n). Flat bx-swizzle regressed +12us: the 2D grid
// already XCD-colocates same-m blocks (y-stride 64 == 0 mod 8) AND keeps each B-panel
// temporally hot chip-wide (all 64 consumers of panel n in one dispatch window).
__global__ __launch_bounds__(512, 1) void k_fc1_8p(const unsigned short* __restrict__ x2b,
                                                   const unsigned short* __restrict__ w1b,
                                                   const float* __restrict__ fc1_b,
                                                   unsigned short* __restrict__ h) {
    extern __shared__ char smem[];
    int tid = threadIdx.x, wave = tid >> 6, lane = tid & 63;
    int m0 = blockIdx.x * 256, n0 = blockIdx.y * 256;
    int rowLoc = wave * 32 + (lane >> 3);
    int cg = ((lane & 7) ^ ((lane >> 3) & 7)) * 8;
    const unsigned short* ap[4];
    const unsigned short* bp[4];
    #pragma unroll
    for (int c = 0; c < 4; ++c) {
        int rr = rowLoc + c * 8;
        ap[c] = x2b + (size_t)(m0 + rr) * V_ + cg;
        bp[c] = w1b + (size_t)(n0 + rr) * V_ + cg;
    }
    f32x4 acc[8][4] = {};
    gemm8<V_ / 64>(ap, bp, smem, wave, lane, acc);
    int wmBase = (wave >> 2) * 128, wnBase = (wave & 3) * 64;
    int lr = lane & 15, quad = lane >> 4;
    #pragma unroll
    for (int i = 0; i < 8; ++i)
        #pragma unroll
        for (int r = 0; r < 4; ++r) {
            size_t row = (size_t)(m0 + wmBase + i * 16 + quad * 4 + r);
            #pragma unroll
            for (int j = 0; j < 4; ++j) {
                int col = n0 + wnBase + j * 16 + lr;
                h[row * FF_ + col] = f2bf(fmaxf(acc[i][j][r] + fc1_b[col], 0.f));
            }
        }
}

// ---------------- fc2: out = h @ fc2W^T + b + x2b (residual), 128^2 structure ----------------
// XCD-chunk swizzle (512 = 8*64) KEPT (R9: -17us or better): the 4 same-m blocks (sharing a
// 512KB h tile, re-read 4x = 268MB logical) co-reside on one XCD's L2.
__global__ __launch_bounds__(256, 3) void k_fc2(const unsigned short* __restrict__ h,
                                                const unsigned short* __restrict__ w2b,
                                                const float* __restrict__ fc2_b,
                                                const unsigned short* __restrict__ x2b,
                                                float* __restrict__ out) {
    __shared__ __align__(16) short As[128 * 64];
    __shared__ __align__(16) short Bs[128 * 64];
    int bx = ((int)(blockIdx.x & 7)) * 64 + (int)(blockIdx.x >> 3);
    int tid = threadIdx.x, wave = tid >> 6, lane = tid & 63;
    int rowLoc = wave * 32 + (lane >> 3);
    int cg = ((lane & 7) ^ ((lane >> 3) & 7)) * 8;
    int m0 = (bx >> 2) * 128, n0 = (bx & 3) * 128;
    const unsigned short* ap[4];
    const unsigned short* bp[4];
    #pragma unroll
    for (int c = 0; c < 4; ++c) {
        int rr = rowLoc + c * 8;
        ap[c] = h + (size_t)(m0 + rr) * FF_ + cg;
        bp[c] = w2b + (size_t)(n0 + rr) * FF_ + cg;
    }
    f32x4 acc[4][4] = {};
    gemm_k_loop64(ap, bp, As, Bs, FF_ / 64, wave, lane, acc);
    int wm = (wave & 1) << 6, wn = (wave >> 1) << 6;
    int lr = lane & 15, quad = lane >> 4;
    #pragma unroll
    for (int i = 0; i < 4; ++i)
        #pragma unroll
        for (int r = 0; r < 4; ++r) {
            size_t row = (size_t)(m0 + wm + i * 16 + quad * 4 + r);
            #pragma unroll
            for (int j = 0; j < 4; ++j) {
                int col = n0 + wn + j * 16 + lr;
                out[row * V_ + col] = acc[i][j][r] + fc2_b[col] + bf2f(x2b[row * V_ + col]);
            }
        }
}

extern "C" void kernel_launch(void* const* d_in, const int* in_sizes, int n_in,
                              void* d_out, int out_size, void* d_ws, size_t ws_size,
                              hipStream_t stream) {
    const float* x      = (const float*)d_in[0];
    const float* gate_W = (const float*)d_in[1];
    const float* exp_W  = (const float*)d_in[2];
    const float* exp_b  = (const float*)d_in[3];
    const float* fc1_W  = (const float*)d_in[4];
    const float* fc1_b  = (const float*)d_in[5];
    const float* fc2_W  = (const float*)d_in[6];
    const float* fc2_b  = (const float*)d_in[7];
    float* out_x = (float*)d_out;
    float* out_p = (float*)d_out + (size_t)B_ * S_ * V_;

    if (ws_size < (size_t)155582592) return;

    char* ws = (char*)d_ws;
    unsigned short* Yb    = (unsigned short*)(ws);             // 33.5 MB used (region 67 MB)
    unsigned short* xt    = (unsigned short*)(ws +  67108864); // 16.7 MB
    unsigned short* x2b   = (unsigned short*)(ws + 117440512); // 16.7 MB
    unsigned short* expWb = (unsigned short*)(ws + 134217728); // 16.7 MB
    unsigned short* fc1Wb = (unsigned short*)(ws + 150994944); //  2 MB
    unsigned short* fc2Wb = (unsigned short*)(ws + 153092096); //  2 MB
    char* route = ws + 155189248;
    int*   cnt     = (int*)(route);
    int*   tok_of  = (int*)(route + 128);
    int*   tk_slot = (int*)(route + 128 + 262144);
    float* tk_w    = (float*)(route + 128 + 262144 + 65536);
    unsigned short* h = (unsigned short*)ws;   // alias: Yb dead after k_combine; h = 67 MB
    double* part = (double*)ws;                // alias: gate partials (4.2 MB) dead before k_moe_gemm

    k_prep<<<dim3(16, 8, 16 + 40), 256, 0, stream>>>(x, gate_W, xt, part, cnt,
                                                     exp_W, expWb, fc1_W, fc1Wb, fc2_W, fc2Wb);
    k_gate_fin<<<dim3(NT_ / 256), 256, 0, stream>>>(part, out_p, cnt, tok_of, tk_slot, tk_w);
    k_moe_gemm<<<dim3(136, S_ / 128), 256, 0, stream>>>(xt, expWb, exp_b, cnt, tok_of, Yb);
    k_combine<<<dim3(V_ / 32, S_ / 32, B_), 256, 0, stream>>>(x, Yb, cnt, tk_slot, tk_w, x2b);
    k_fc1_8p<<<dim3(NR_ / 256, FF_ / 256), 512, 131072, stream>>>(x2b, fc1Wb, fc1_b, h);
    k_fc2<<<dim3(512), 256, 0, stream>>>(h, fc2Wb, fc2_b, x2b, out_x);
}

// Round 12
// 297.237 us; speedup vs baseline: 1.0351x; 1.0351x over previous
//
#include <hip/hip_runtime.h>
#include <stdint.h>

#define B_  16
#define V_  512
#define S_  1024
#define E_  8
#define FF_ 2048
#define NT_ (B_*V_)    // 8192 tokens (b,v)
#define NR_ (B_*S_)    // 16384 rows (b,s)

typedef __attribute__((ext_vector_type(8))) short bf16x8;   // 8 bf16 = 4 VGPRs
typedef __attribute__((ext_vector_type(4))) float f32x4;

__device__ __forceinline__ unsigned short f2bf(float f) {
    unsigned int u = __float_as_uint(f);
    u += 0x7FFFu + ((u >> 16) & 1u);          // round-to-nearest-even
    return (unsigned short)(u >> 16);
}
__device__ __forceinline__ float bf2f(unsigned short u) {
    return __uint_as_float(((unsigned int)u) << 16);
}

__device__ __forceinline__ void gl_lds16(const void* g, void* l) {
    // async global->LDS, 16B per lane; LDS dest = wave-uniform base + lane*16
    __builtin_amdgcn_global_load_lds((const __attribute__((address_space(1))) void*)g,
                                     (__attribute__((address_space(3))) void*)l,
                                     16, 0, 0);
}

// ---------------- fused prep: weight fp32->bf16 convert  +  xt transpose  +  gate partials ----------------
__device__ __forceinline__ void cvt4(const float* s, unsigned short* d, int i) {
    float4 v = *(const float4*)(s + i);
    ushort4 o; o.x = f2bf(v.x); o.y = f2bf(v.y); o.z = f2bf(v.z); o.w = f2bf(v.w);
    *(ushort4*)(d + i) = o;
}
// grid (16, 8, 56): z<16 -> xt_gate path (b=z, sc=y, vt=x);
// z>=16 -> convert path, linear id = (z-16)*128 + y*16 + x in [0,5120), 2 float4-groups each.
__global__ __launch_bounds__(256) void k_prep(const float* __restrict__ x,
                                              const float* __restrict__ gate_W,
                                              unsigned short* __restrict__ xt,
                                              double* __restrict__ part,
                                              int* __restrict__ cnt,
                                              const float* __restrict__ expW, unsigned short* __restrict__ expWb,
                                              const float* __restrict__ fc1W, unsigned short* __restrict__ fc1Wb,
                                              const float* __restrict__ fc2W, unsigned short* __restrict__ fc2Wb) {
    int tid = threadIdx.x;
    if (blockIdx.z >= 16) {
        int cid = ((int)blockIdx.z - 16) * 128 + (int)blockIdx.y * 16 + (int)blockIdx.x;
        #pragma unroll
        for (int rep = 0; rep < 2; ++rep) {
            int g = (cid + rep * 5120) * 256 + tid;          // [0, 2621440)
            if (g < 2097152)              cvt4(expW, expWb, g * 4);
            else if (g < 2097152 + 262144) cvt4(fc1W, fc1Wb, (g - 2097152) * 4);
            else                           cvt4(fc2W, fc2Wb, (g - 2097152 - 262144) * 4);
        }
        return;
    }
    __shared__ float t[32][33];
    __shared__ float gw[E_][128];
    int b = blockIdx.z, sc = blockIdx.y, vt = blockIdx.x;   // sc: 128-s chunk
    if (vt == 0 && sc == 0 && b == 0 && tid < E_) cnt[tid] = 0;
    int col = tid & 31, row8 = tid >> 5;
    for (int i = tid; i < E_ * 128; i += 256) {
        int e = i >> 7, j = i & 127;
        gw[e][j] = gate_W[e * S_ + sc * 128 + j];
    }
    double acc = 0.0;
    for (int sub = 0; sub < 4; ++sub) {
        int s0 = sc * 128 + sub * 32;
        __syncthreads();                       // gw ready (sub=0) / t readers done (sub>0)
        for (int r = 0; r < 4; ++r) {
            int sl = row8 + r * 8;
            t[sl][col] = x[(b * S_ + s0 + sl) * V_ + vt * 32 + col];   // t[s][v]
        }
        __syncthreads();
        for (int r = 0; r < 4; ++r) {
            int vl = row8 + r * 8;
            xt[(size_t)(b * V_ + vt * 32 + vl) * S_ + s0 + col] = f2bf(t[col][vl]);
        }
        #pragma unroll
        for (int s = 0; s < 32; ++s)
            acc += (double)t[s][col] * (double)gw[row8][sub * 32 + s];
    }
    int tok = b * V_ + vt * 32 + col;
    part[((size_t)sc * NT_ + tok) * E_ + row8] = acc;
}

// ---------------- gating stage B: reduce 8 chunks, softmax, top-2, routing ----------------
__global__ __launch_bounds__(256) void k_gate_fin(const double* __restrict__ part,
                                                  float* __restrict__ probs_out,
                                                  int* __restrict__ cnt, int* __restrict__ tok_of,
                                                  int* __restrict__ tk_slot, float* __restrict__ tk_w) {
    int t = blockIdx.x * 256 + threadIdx.x;
    int lane = threadIdx.x & 63;
    double l[E_];
    #pragma unroll
    for (int e = 0; e < E_; ++e) l[e] = 0.0;
    for (int c = 0; c < S_ / 128; ++c) {
        const double* p = part + ((size_t)c * NT_ + t) * E_;
        #pragma unroll
        for (int e = 0; e < E_; ++e) l[e] += p[e];
    }
    double m = l[0];
    #pragma unroll
    for (int e = 1; e < E_; ++e) m = l[e] > m ? l[e] : m;
    double p[E_], sum = 0.0;
    #pragma unroll
    for (int e = 0; e < E_; ++e) { p[e] = exp(l[e] - m); sum += p[e]; }
    float pf[E_];
    #pragma unroll
    for (int e = 0; e < E_; ++e) pf[e] = (float)(p[e] / sum);
    float4 pa = {pf[0], pf[1], pf[2], pf[3]}, pb = {pf[4], pf[5], pf[6], pf[7]};
    *(float4*)(probs_out + (size_t)t * E_) = pa;
    *(float4*)(probs_out + (size_t)t * E_ + 4) = pb;
    int i0 = 0;
    #pragma unroll
    for (int e = 1; e < E_; ++e) if (pf[e] > pf[i0]) i0 = e;
    int i1 = -1;
    #pragma unroll
    for (int e = 0; e < E_; ++e) if (e != i0 && (i1 < 0 || pf[e] > pf[i1])) i1 = e;
    int sel[2] = {i0, i1};
    float wsel[2] = {pf[i0], pf[i1]};
    #pragma unroll
    for (int k = 0; k < 2; ++k) {
        int ie = sel[k];
        int pos = 0;
        for (int e = 0; e < E_; ++e) {                       // uniform loop, ballot legal
            unsigned long long msk = __ballot(ie == e);
            if (ie == e) {
                int rank = __popcll(msk & ((1ull << lane) - 1ull));
                int leader = __ffsll((long long)msk) - 1;
                int base = 0;
                if (lane == leader) base = atomicAdd(&cnt[e], __popcll(msk));
                base = __shfl(base, leader);
                pos = base + rank;
            }
        }
        tok_of[ie * NT_ + pos] = t;
        tk_slot[t * 2 + k] = (ie << 16) | pos;
        tk_w[t * 2 + k] = wsel[k];
    }
}

// ---------------- 128^2 K-loop (known-good): BK=64, 16x16x32 MFMA, XOR-swizzled LDS ----------------
__device__ __forceinline__ void gemm_k_loop64(const unsigned short* (&ap)[4],
                                              const unsigned short* (&bp)[4],
                                              short* As, short* Bs, int kIters, int wave, int lane,
                                              f32x4 (&acc)[4][4]) {
    char* ldsA = (char*)As + wave * 4096;
    char* ldsB = (char*)Bs + wave * 4096;
    int wm = (wave & 1) << 6, wn = (wave >> 1) << 6;
    int lr = lane & 15, quad = lane >> 4;
    int pb = (quad ^ (lr & 7)) * 8;
    const unsigned short* a0 = ap[0]; const unsigned short* a1 = ap[1];
    const unsigned short* a2 = ap[2]; const unsigned short* a3 = ap[3];
    const unsigned short* b0 = bp[0]; const unsigned short* b1 = bp[1];
    const unsigned short* b2 = bp[2]; const unsigned short* b3 = bp[3];
    for (int kk = 0; kk < kIters; ++kk) {
        gl_lds16(a0, ldsA);        gl_lds16(a1, ldsA + 1024);
        gl_lds16(a2, ldsA + 2048); gl_lds16(a3, ldsA + 3072);
        gl_lds16(b0, ldsB);        gl_lds16(b1, ldsB + 1024);
        gl_lds16(b2, ldsB + 2048); gl_lds16(b3, ldsB + 3072);
        a0 += 64; a1 += 64; a2 += 64; a3 += 64;
        b0 += 64; b1 += 64; b2 += 64; b3 += 64;
        __syncthreads();
        #pragma unroll
        for (int ks = 0; ks < 2; ++ks) {
            int po = pb ^ (ks << 5);
            bf16x8 af[4], bfv[4];
            #pragma unroll
            for (int i = 0; i < 4; ++i)
                af[i] = *(const bf16x8*)(As + (wm + i * 16 + lr) * 64 + po);
            #pragma unroll
            for (int j = 0; j < 4; ++j)
                bfv[j] = *(const bf16x8*)(Bs + (wn + j * 16 + lr) * 64 + po);
            #pragma unroll
            for (int i = 0; i < 4; ++i)
                #pragma unroll
                for (int j = 0; j < 4; ++j)
                    acc[i][j] = __builtin_amdgcn_mfma_f32_16x16x32_bf16(af[i], bfv[j], acc[i][j], 0, 0, 0);
        }
        __syncthreads();
    }
}

// ---------------- MoE gather-GEMM: Yb = bf16(xt[tok] @ expW[e]^T + exp_b) ----------------
// launch_bounds(256,3): reg footprint ~72 arch VGPR + 64 acc AGPR = 136/wave -> 3 waves/SIMD
// ceiling. (256,5) spills acc (R4: WRITE_SIZE 33->591 MB). Do not raise.
__global__ __launch_bounds__(256, 3) void k_moe_gemm(const unsigned short* __restrict__ xt,
                                                     const unsigned short* __restrict__ expWb,
                                                     const float* __restrict__ exp_b,
                                                     const int* __restrict__ cnt,
                                                     const int* __restrict__ tok_of,
                                                     unsigned short* __restrict__ Yb) {
    int bx = ((int)(blockIdx.x & 7)) * 17 + (int)(blockIdx.x >> 3);   // 136 = 8*17 bijective XCD swizzle
    int e = -1, pos0 = 0, yrow0 = 0, ne = 0;
    {
        int tb = 0, o = 0;
        #pragma unroll
        for (int i = 0; i < E_; ++i) {
            int ci = cnt[i];
            int nti = (ci + 127) >> 7;
            if (e < 0 && bx < tb + nti) { e = i; pos0 = (bx - tb) * 128; yrow0 = o; ne = ci; }
            tb += nti; o += ci;
        }
    }
    if (e < 0) return;
    int nt = blockIdx.y;
    __shared__ __align__(16) short As[128 * 64];   // 16 KB
    __shared__ __align__(16) short Bs[128 * 64];   // 16 KB
    int tid = threadIdx.x, wave = tid >> 6, lane = tid & 63;
    int rowLoc = wave * 32 + (lane >> 3);
    int cg = ((lane & 7) ^ ((lane >> 3) & 7)) * 8;
    const unsigned short* Wb = expWb + (size_t)e * S_ * S_;
    const unsigned short* ap[4];
    const unsigned short* bp[4];
    #pragma unroll
    for (int c = 0; c < 4; ++c) {
        int rr = rowLoc + c * 8;
        int tok = tok_of[e * NT_ + min(pos0 + rr, ne - 1)];
        ap[c] = xt + (size_t)tok * S_ + cg;
        bp[c] = Wb + (size_t)(nt * 128 + rr) * S_ + cg;
    }
    f32x4 acc[4][4] = {};
    gemm_k_loop64(ap, bp, As, Bs, S_ / 64, wave, lane, acc);
    int wm = (wave & 1) << 6, wn = (wave >> 1) << 6;
    int lr = lane & 15, quad = lane >> 4;
    #pragma unroll
    for (int i = 0; i < 4; ++i)
        #pragma unroll
        for (int r = 0; r < 4; ++r) {
            int pos = pos0 + wm + i * 16 + quad * 4 + r;
            if (pos < ne) {
                size_t row = (size_t)(yrow0 + pos);
                #pragma unroll
                for (int j = 0; j < 4; ++j) {
                    int col = nt * 128 + wn + j * 16 + lr;
                    Yb[row * S_ + col] = f2bf(acc[i][j][r] + exp_b[e * S_ + col]);
                }
            }
        }
}

// ---------------- combine: x2b[b,s,v] = bf16(x + relu(w0*Y0 + w1*Y1)) ----------------
__global__ void k_combine(const float* __restrict__ x, const unsigned short* __restrict__ Yb,
                          const int* __restrict__ cnt, const int* __restrict__ tk_slot,
                          const float* __restrict__ tk_w,
                          unsigned short* __restrict__ x2b) {
    __shared__ float t[32][33];
    int b = blockIdx.z, st = blockIdx.y, vt = blockIdx.x;
    int tid = threadIdx.x;
    int vl = tid >> 3, sq = (tid & 7) * 4;
    int tok = b * V_ + vt * 32 + vl;
    int s0 = tk_slot[tok * 2 + 0], s1 = tk_slot[tok * 2 + 1];
    float w0 = tk_w[tok * 2 + 0], w1 = tk_w[tok * 2 + 1];
    int e0 = s0 >> 16, e1 = s1 >> 16;
    int r0b = 0, r1b = 0, o = 0;
    #pragma unroll
    for (int i = 0; i < E_; ++i) {
        if (i == e0) r0b = o;
        if (i == e1) r1b = o;
        o += cnt[i];
    }
    size_t r0 = (size_t)(r0b + (s0 & 0xFFFF));
    size_t r1 = (size_t)(r1b + (s1 & 0xFFFF));
    int sg = st * 32 + sq;
    ushort4 y0 = *(const ushort4*)(Yb + r0 * S_ + sg);
    ushort4 y1 = *(const ushort4*)(Yb + r1 * S_ + sg);
    t[vl][sq + 0] = fmaxf(w0 * bf2f(y0.x) + w1 * bf2f(y1.x), 0.f);
    t[vl][sq + 1] = fmaxf(w0 * bf2f(y0.y) + w1 * bf2f(y1.y), 0.f);
    t[vl][sq + 2] = fmaxf(w0 * bf2f(y0.z) + w1 * bf2f(y1.z), 0.f);
    t[vl][sq + 3] = fmaxf(w0 * bf2f(y0.w) + w1 * bf2f(y1.w), 0.f);
    __syncthreads();
    int vcol = tid & 31, srow8 = tid >> 5;
    for (int r = 0; r < 4; ++r) {
        int sl = srow8 + r * 8;
        size_t gi = (size_t)(b * S_ + st * 32 + sl) * V_ + vt * 32 + vcol;
        x2b[gi] = f2bf(x[gi] + t[vcol][sl]);
    }
}

// ================= 256x256 8-wave deep-pipelined GEMM (fc1) =================
__device__ __forceinline__ void stage8(const unsigned short* (&ap)[4],
                                       const unsigned short* (&bp)[4],
                                       char* ldsA, char* ldsB, int kt, int wave) {
    const int off = kt * 64;                  // shorts
    char* la = ldsA + wave * 4096;            // wave stages rows [wave*32, +32): 4 x 1KB
    char* lb = ldsB + wave * 4096;
    gl_lds16(ap[0] + off, la);
    gl_lds16(ap[1] + off, la + 1024);
    gl_lds16(ap[2] + off, la + 2048);
    gl_lds16(ap[3] + off, la + 3072);
    gl_lds16(bp[0] + off, lb);
    gl_lds16(bp[1] + off, lb + 1024);
    gl_lds16(bp[2] + off, lb + 2048);
    gl_lds16(bp[3] + off, lb + 3072);
}

template<bool LAST>
__device__ __forceinline__ void body64(const short* As, const short* Bs,
                                       int wmBase, int wnBase, int lr, int pb,
                                       f32x4 (&acc)[8][4]) {
    if (LAST) asm volatile("s_waitcnt vmcnt(0)" ::: "memory");
    else      asm volatile("s_waitcnt vmcnt(8)" ::: "memory");
    __builtin_amdgcn_s_barrier();
    __builtin_amdgcn_sched_barrier(0);
    bf16x8 bfv[4][2];
    #pragma unroll
    for (int j = 0; j < 4; ++j)
        #pragma unroll
        for (int ks = 0; ks < 2; ++ks)
            bfv[j][ks] = *(const bf16x8*)(Bs + (wnBase + j * 16 + lr) * 64 + (pb ^ (ks << 5)));
    #pragma unroll
    for (int q = 0; q < 4; ++q) {
        bf16x8 af[2][2];
        #pragma unroll
        for (int f = 0; f < 2; ++f)
            #pragma unroll
            for (int ks = 0; ks < 2; ++ks)
                af[f][ks] = *(const bf16x8*)(As + (wmBase + q * 32 + f * 16 + lr) * 64 + (pb ^ (ks << 5)));
        __builtin_amdgcn_s_barrier();
        __builtin_amdgcn_s_setprio(1);
        #pragma unroll
        for (int f = 0; f < 2; ++f)
            #pragma unroll
            for (int j = 0; j < 4; ++j)
                #pragma unroll
                for (int ks = 0; ks < 2; ++ks)
                    acc[q * 2 + f][j] = __builtin_amdgcn_mfma_f32_16x16x32_bf16(
                        af[f][ks], bfv[j][ks], acc[q * 2 + f][j], 0, 0, 0);
        __builtin_amdgcn_s_setprio(0);
        __builtin_amdgcn_s_barrier();
    }
}

template<int KT>
__device__ __forceinline__ void gemm8(const unsigned short* (&ap)[4],
                                      const unsigned short* (&bp)[4],
                                      char* smem, int wave, int lane,
                                      f32x4 (&acc)[8][4]) {
    char* A0 = smem;           char* B0 = smem + 32768;
    char* A1 = smem + 65536;   char* B1 = smem + 98304;
    const int wmBase = (wave >> 2) * 128;     // 2 M-waves x 4 N-waves
    const int wnBase = (wave & 3) * 64;
    const int lr = lane & 15;
    const int pb = ((lane >> 4) ^ (lr & 7)) * 8;
    stage8(ap, bp, A0, B0, 0, wave);
    stage8(ap, bp, A1, B1, 1, wave);
    for (int kt = 0; kt + 2 < KT; kt += 2) {
        body64<false>((const short*)A0, (const short*)B0, wmBase, wnBase, lr, pb, acc);
        stage8(ap, bp, A0, B0, kt + 2, wave);
        body64<false>((const short*)A1, (const short*)B1, wmBase, wnBase, lr, pb, acc);
        stage8(ap, bp, A1, B1, kt + 3, wave);
    }
    body64<false>((const short*)A0, (const short*)B0, wmBase, wnBase, lr, pb, acc);
    body64<true >((const short*)A1, (const short*)B1, wmBase, wnBase, lr, pb, acc);
}

// ---------------- fc1 (8-phase 256^2): h = relu(x2b @ fc1W^T + b) -> bf16 ----------------
// R9 LESSON: keep the 2D grid (x=m fast, y=n). Flat bx-swizzle regressed +12us.
// NOTE: 2D grid => m-band m dispatched to XCD m%8 (interleaved) — fc2's swizzle must match.
__global__ __launch_bounds__(512, 1) void k_fc1_8p(const unsigned short* __restrict__ x2b,
                                                   const unsigned short* __restrict__ w1b,
                                                   const float* __restrict__ fc1_b,
                                                   unsigned short* __restrict__ h) {
    extern __shared__ char smem[];
    int tid = threadIdx.x, wave = tid >> 6, lane = tid & 63;
    int m0 = blockIdx.x * 256, n0 = blockIdx.y * 256;
    int rowLoc = wave * 32 + (lane >> 3);
    int cg = ((lane & 7) ^ ((lane >> 3) & 7)) * 8;
    const unsigned short* ap[4];
    const unsigned short* bp[4];
    #pragma unroll
    for (int c = 0; c < 4; ++c) {
        int rr = rowLoc + c * 8;
        ap[c] = x2b + (size_t)(m0 + rr) * V_ + cg;
        bp[c] = w1b + (size_t)(n0 + rr) * V_ + cg;
    }
    f32x4 acc[8][4] = {};
    gemm8<V_ / 64>(ap, bp, smem, wave, lane, acc);
    int wmBase = (wave >> 2) * 128, wnBase = (wave & 3) * 64;
    int lr = lane & 15, quad = lane >> 4;
    #pragma unroll
    for (int i = 0; i < 8; ++i)
        #pragma unroll
        for (int r = 0; r < 4; ++r) {
            size_t row = (size_t)(m0 + wmBase + i * 16 + quad * 4 + r);
            #pragma unroll
            for (int j = 0; j < 4; ++j) {
                int col = n0 + wnBase + j * 16 + lr;
                h[row * FF_ + col] = f2bf(fmaxf(acc[i][j][r] + fc1_b[col], 0.f));
            }
        }
}

// ---------------- fc2: out = h @ fc2W^T + b + x2b (residual), 128^2 structure ----------------
// R11 LESSON: fc2's h-locality swizzle must ALIGN WITH fc1's h WRITE distribution.
// fc1 2D grid writes fc1-band f (256 rows) on XCD f%8 (interleaved). fc2-band mf (128 rows)
// belongs to fc1-band mf>>1 -> want XCD (mf>>1)%8. Decode (bijective, 8*8*2*4=512):
//   k=bid&7 (XCD), l=bid>>3, t=l>>3, r=l&7 -> mf = 16t + 2k + (r>>2), n = r&3.
// n iterates fastest: each h-tile's 4 consumers temporally adjacent on the writing XCD.
__global__ __launch_bounds__(256, 3) void k_fc2(const unsigned short* __restrict__ h,
                                                const unsigned short* __restrict__ w2b,
                                                const float* __restrict__ fc2_b,
                                                const unsigned short* __restrict__ x2b,
                                                float* __restrict__ out) {
    __shared__ __align__(16) short As[128 * 64];
    __shared__ __align__(16) short Bs[128 * 64];
    int bid = (int)blockIdx.x;
    int k = bid & 7, l = bid >> 3;
    int t = l >> 3, r = l & 7;
    int mf = 16 * t + 2 * k + (r >> 2);
    int m0 = mf * 128, n0 = (r & 3) * 128;
    int tid = threadIdx.x, wave = tid >> 6, lane = tid & 63;
    int rowLoc = wave * 32 + (lane >> 3);
    int cg = ((lane & 7) ^ ((lane >> 3) & 7)) * 8;
    const unsigned short* ap[4];
    const unsigned short* bp[4];
    #pragma unroll
    for (int c = 0; c < 4; ++c) {
        int rr = rowLoc + c * 8;
        ap[c] = h + (size_t)(m0 + rr) * FF_ + cg;
        bp[c] = w2b + (size_t)(n0 + rr) * FF_ + cg;
    }
    f32x4 acc[4][4] = {};
    gemm_k_loop64(ap, bp, As, Bs, FF_ / 64, wave, lane, acc);
    int wm = (wave & 1) << 6, wn = (wave >> 1) << 6;
    int lr = lane & 15, quad = lane >> 4;
    #pragma unroll
    for (int i = 0; i < 4; ++i)
        #pragma unroll
        for (int rr2 = 0; rr2 < 4; ++rr2) {
            size_t row = (size_t)(m0 + wm + i * 16 + quad * 4 + rr2);
            #pragma unroll
            for (int j = 0; j < 4; ++j) {
                int col = n0 + wn + j * 16 + lr;
                out[row * V_ + col] = acc[i][j][rr2] + fc2_b[col] + bf2f(x2b[row * V_ + col]);
            }
        }
}

extern "C" void kernel_launch(void* const* d_in, const int* in_sizes, int n_in,
                              void* d_out, int out_size, void* d_ws, size_t ws_size,
                              hipStream_t stream) {
    const float* x      = (const float*)d_in[0];
    const float* gate_W = (const float*)d_in[1];
    const float* exp_W  = (const float*)d_in[2];
    const float* exp_b  = (const float*)d_in[3];
    const float* fc1_W  = (const float*)d_in[4];
    const float* fc1_b  = (const float*)d_in[5];
    const float* fc2_W  = (const float*)d_in[6];
    const float* fc2_b  = (const float*)d_in[7];
    float* out_x = (float*)d_out;
    float* out_p = (float*)d_out + (size_t)B_ * S_ * V_;

    if (ws_size < (size_t)155582592) return;

    char* ws = (char*)d_ws;
    unsigned short* Yb    = (unsigned short*)(ws);             // 33.5 MB used (region 67 MB)
    unsigned short* xt    = (unsigned short*)(ws +  67108864); // 16.7 MB
    unsigned short* x2b   = (unsigned short*)(ws + 117440512); // 16.7 MB
    unsigned short* expWb = (unsigned short*)(ws + 134217728); // 16.7 MB
    unsigned short* fc1Wb = (unsigned short*)(ws + 150994944); //  2 MB
    unsigned short* fc2Wb = (unsigned short*)(ws + 153092096); //  2 MB
    char* route = ws + 155189248;
    int*   cnt     = (int*)(route);
    int*   tok_of  = (int*)(route + 128);
    int*   tk_slot = (int*)(route + 128 + 262144);
    float* tk_w    = (float*)(route + 128 + 262144 + 65536);
    unsigned short* h = (unsigned short*)ws;   // alias: Yb dead after k_combine; h = 67 MB
    double* part = (double*)ws;                // alias: gate partials (4.2 MB) dead before k_moe_gemm

    k_prep<<<dim3(16, 8, 16 + 40), 256, 0, stream>>>(x, gate_W, xt, part, cnt,
                                                     exp_W, expWb, fc1_W, fc1Wb, fc2_W, fc2Wb);
    k_gate_fin<<<dim3(NT_ / 256), 256, 0, stream>>>(part, out_p, cnt, tok_of, tk_slot, tk_w);
    k_moe_gemm<<<dim3(136, S_ / 128), 256, 0, stream>>>(xt, expWb, exp_b, cnt, tok_of, Yb);
    k_combine<<<dim3(V_ / 32, S_ / 32, B_), 256, 0, stream>>>(x, Yb, cnt, tk_slot, tk_w, x2b);
    k_fc1_8p<<<dim3(NR_ / 256, FF_ / 256), 512, 131072, stream>>>(x2b, fc1Wb, fc1_b, h);
    k_fc2<<<dim3(512), 256, 0, stream>>>(h, fc2Wb, fc2_b, x2b, out_x);
}